// Round 1
// baseline (560.424 us; speedup 1.0000x reference)
//
#include <hip/hip_runtime.h>
#include <hip/hip_bf16.h>

// Backward (bilinear) warp: out[b,c,h,w] = bilinear_sample(input[b,c], w+flow_x, h+flow_y)
// Shapes: input [4,32,512,512] f32, flow [4,2,512,512] f32, out [4,32,512,512] f32.
// Memory-bound: compulsory traffic ~277 MB -> ~44 us floor at 6.3 TB/s.
//
// Strategy: one thread per pixel (b,h,w); bilinear weights computed once and
// reused across all C=32 channels. Stores coalesced along w; gather taps are
// spatially local (flow ~ N(0,1)*8 px), input fits in L3.

constexpr int B = 4, C = 32, H = 512, W = 512;
constexpr int HW = H * W;

__global__ __launch_bounds__(256) void warp_kernel(
    const float* __restrict__ input,
    const float* __restrict__ flow,
    float* __restrict__ out)
{
    int idx = blockIdx.x * blockDim.x + threadIdx.x;   // pixel index in [0, B*H*W)
    if (idx >= B * HW) return;

    int w = idx & (W - 1);
    int h = (idx >> 9) & (H - 1);
    int b = idx >> 18;

    int pix = h * W + w;
    float fx = flow[(b * 2 + 0) * HW + pix];
    float fy = flow[(b * 2 + 1) * HW + pix];

    // clip sample coords to [0, dim-1]
    float x = fminf(fmaxf((float)w + fx, 0.0f), (float)(W - 1));
    float y = fminf(fmaxf((float)h + fy, 0.0f), (float)(H - 1));

    float x0f = floorf(x);
    float y0f = floorf(y);
    int x0 = (int)x0f;
    int y0 = (int)y0f;
    int x1 = min(x0 + 1, W - 1);   // clip(x0f+1, 0, W-1); x0f >= 0 always
    int y1 = min(y0 + 1, H - 1);

    // weights use UNCLAMPED x1f=x0f+1, y1f=y0f+1 (matches reference)
    float dx = x - x0f;
    float dy = y - y0f;
    float wa = (1.0f - dx) * (1.0f - dy);
    float wb = (1.0f - dx) * dy;
    float wc = dx * (1.0f - dy);
    float wd = dx * dy;

    int o00 = y0 * W + x0;
    int o10 = y1 * W + x0;
    int o01 = y0 * W + x1;
    int o11 = y1 * W + x1;

    const float* __restrict__ ibase = input + (size_t)b * C * HW;
    float* __restrict__ obase = out + (size_t)b * C * HW;

    #pragma unroll 4
    for (int c = 0; c < C; ++c) {
        const float* __restrict__ p = ibase + c * HW;
        float Ia = p[o00];
        float Ib = p[o10];
        float Ic = p[o01];
        float Id = p[o11];
        obase[c * HW + pix] = wa * Ia + wb * Ib + wc * Ic + wd * Id;
    }
}

extern "C" void kernel_launch(void* const* d_in, const int* in_sizes, int n_in,
                              void* d_out, int out_size, void* d_ws, size_t ws_size,
                              hipStream_t stream) {
    const float* input = (const float*)d_in[0];
    const float* flow  = (const float*)d_in[1];
    float* out = (float*)d_out;

    int n_pix = B * HW;                 // 1,048,576
    int block = 256;
    int grid = (n_pix + block - 1) / block;  // 4096
    warp_kernel<<<grid, block, 0, stream>>>(input, flow, out);
}

// Round 2
// 542.977 us; speedup vs baseline: 1.0321x; 1.0321x over previous
//
#include <hip/hip_runtime.h>
#include <hip/hip_bf16.h>

// Backward (bilinear) warp: out[b,c,h,w] = bilinear_sample(input[b,c], w+flow_x, h+flow_y)
// Shapes: input [4,32,512,512] f32, flow [4,2,512,512] f32, out [4,32,512,512] f32.
//
// R1 post-mortem: 410 us, VALUBusy 2.3%, HBM 1.75 TB/s (22%), FETCH 568 MB vs
// 136 MB compulsory -> latency-bound gather + cross-XCD L2 duplication.
// R2 changes:
//   1. Explicit 8-channel load batching into register arrays -> 32 loads in
//      flight per wave (VGPR was 32, compiler had serialized the pipeline).
//   2. XCD slab swizzle: blockIdx & 7 = XCD (round-robin dispatch), each XCD
//      works a contiguous 512-block pixel slab so overlapping tap lines are
//      reused within one L2 instead of fetched by all 8.

constexpr int B = 4, C = 32, H = 512, W = 512;
constexpr int HW = H * W;
constexpr int NPIX = B * HW;

__global__ __launch_bounds__(256) void warp_kernel(
    const float* __restrict__ input,
    const float* __restrict__ flow,
    float* __restrict__ out)
{
    // XCD slab swizzle: grid is 4096 blocks; dispatch round-robins XCD = bid%8.
    // Remap so XCD k processes contiguous blocks [k*512, (k+1)*512).
    int bid = blockIdx.x;
    int nslab = gridDim.x >> 3;                 // 512
    int pixel_block = (bid & 7) * nslab + (bid >> 3);

    int idx = pixel_block * 256 + (int)threadIdx.x;
    if (idx >= NPIX) return;

    int w = idx & (W - 1);
    int h = (idx >> 9) & (H - 1);
    int b = idx >> 18;

    int pix = h * W + w;
    float fx = flow[(b * 2 + 0) * HW + pix];
    float fy = flow[(b * 2 + 1) * HW + pix];

    float x = fminf(fmaxf((float)w + fx, 0.0f), (float)(W - 1));
    float y = fminf(fmaxf((float)h + fy, 0.0f), (float)(H - 1));

    float x0f = floorf(x);
    float y0f = floorf(y);
    int x0 = (int)x0f;
    int y0 = (int)y0f;
    int x1 = min(x0 + 1, W - 1);
    int y1 = min(y0 + 1, H - 1);

    // weights use UNCLAMPED x1f=x0f+1, y1f=y0f+1 (matches reference)
    float dx = x - x0f;
    float dy = y - y0f;
    float wa = (1.0f - dx) * (1.0f - dy);
    float wb = (1.0f - dx) * dy;
    float wc = dx * (1.0f - dy);
    float wd = dx * dy;

    int o00 = y0 * W + x0;
    int o10 = y1 * W + x0;
    int o01 = y0 * W + x1;
    int o11 = y1 * W + x1;

    const float* __restrict__ ibase = input + (size_t)b * C * HW;
    float* __restrict__ obase = out + (size_t)b * C * HW + pix;

    // 4 groups of 8 channels: 32 independent loads in flight per group.
    #pragma unroll 1
    for (int cg = 0; cg < C; cg += 8) {
        float Ia[8], Ib[8], Ic[8], Id[8];
        #pragma unroll
        for (int u = 0; u < 8; ++u) {
            const float* __restrict__ p = ibase + (cg + u) * HW;
            Ia[u] = p[o00];
            Ib[u] = p[o10];
            Ic[u] = p[o01];
            Id[u] = p[o11];
        }
        #pragma unroll
        for (int u = 0; u < 8; ++u) {
            obase[(cg + u) * HW] = wa * Ia[u] + wb * Ib[u] + wc * Ic[u] + wd * Id[u];
        }
    }
}

extern "C" void kernel_launch(void* const* d_in, const int* in_sizes, int n_in,
                              void* d_out, int out_size, void* d_ws, size_t ws_size,
                              hipStream_t stream) {
    const float* input = (const float*)d_in[0];
    const float* flow  = (const float*)d_in[1];
    float* out = (float*)d_out;

    int block = 256;
    int grid = (NPIX + block - 1) / block;  // 4096, divisible by 8
    warp_kernel<<<grid, block, 0, stream>>>(input, flow, out);
}

// Round 3
// 345.004 us; speedup vs baseline: 1.6244x; 1.5738x over previous
//
#include <hip/hip_runtime.h>
#include <hip/hip_bf16.h>

// Backward (bilinear) warp: out[b,c,h,w] = bilinear_sample(input[b,c], w+flow_x, h+flow_y)
// Shapes: input [4,32,512,512] f32, flow [4,2,512,512] f32, out [4,32,512,512] f32.
//
// R2 post-mortem: 381 us, VALUBusy 2%, HBM 0.6 TB/s -> NOT bandwidth-bound.
// Gather-pipe bound: per 64-lane load, lanes hit ~50-64 distinct cache lines
// (y0 diverges across ~+-24 rows), serialized ~1 line/cyc in TA, 4 B useful
// per line. 128M line transactions / 256 CU ~ 210+ us floor. Fix: gather from
// LDS instead. Block = one 64x64 pixel tile; stage the tile's input region
// (+-40 px apron, >5 sigma of flow ~ N(0,8)) into LDS per channel with
// coalesced float4 loads; all taps become LDS reads (ds_read2 pairs).
// Outliers (|flow|>40, P~5e-7) take a rare per-lane global fallback.

constexpr int B = 4, C = 32, H = 512, W = 512;
constexpr int HW = H * W;
constexpr int TILE = 64;
constexpr int APRON = 40;
constexpr int LSTRIDE = 148;                  // dwords per LDS row (mult of 4)
constexpr int RHMAX = TILE + 2 * APRON + 1;   // 145 rows max
// max region width: align-down of (tx0-40) adds <=3 -> 64+81+3 = 148 = LSTRIDE

__global__ __launch_bounds__(1024, 1) void warp_tile_kernel(
    const float* __restrict__ input,
    const float* __restrict__ flow,
    float* __restrict__ out)
{
    __shared__ float s[RHMAX * LSTRIDE + 8];  // +pad: edge ds_read2 can touch +1

    int bid = blockIdx.x;                 // 256 blocks = [b:4][ty:8][tx:8]
    int tx = bid & 7;
    int ty = (bid >> 3) & 7;
    int b  = bid >> 6;
    int tx0 = tx * TILE, ty0 = ty * TILE;

    // staged region (x start aligned down to 4 for float4 loads)
    int rx0 = max(0, tx0 - APRON) & ~3;
    int rx1 = min(W - 1, tx0 + TILE + APRON);  // covers x1 = x0+1 taps
    int ry0 = max(0, ty0 - APRON);
    int ry1 = min(H - 1, ty0 + TILE + APRON);
    int rw = rx1 - rx0 + 1;
    int rh = ry1 - ry0 + 1;

    int tid = (int)threadIdx.x;
    int cl = tid & 63;          // col within tile
    int rl = tid >> 6;          // row group within tile (0..15); px rows rl+16p

    // ---- per-pixel precompute (4 px per thread), reused across 32 channels ----
    float wa[4], wb_[4], wc_[4], wd_[4];
    int a0[4], a1[4];
    int opix0 = (ty0 + rl) * W + tx0 + cl;

    #pragma unroll
    for (int p = 0; p < 4; ++p) {
        int h = ty0 + rl + 16 * p;
        int w = tx0 + cl;
        int pix = h * W + w;
        float fx = flow[(b * 2 + 0) * HW + pix];
        float fy = flow[(b * 2 + 1) * HW + pix];
        float x = fminf(fmaxf((float)w + fx, 0.0f), (float)(W - 1));
        float y = fminf(fmaxf((float)h + fy, 0.0f), (float)(H - 1));
        float x0f = floorf(x), y0f = floorf(y);
        int x0 = (int)x0f, y0 = (int)y0f;
        int x1 = min(x0 + 1, W - 1), y1 = min(y0 + 1, H - 1);
        float dx = x - x0f, dy = y - y0f;
        // weights use UNCLAMPED x1f=x0f+1, y1f=y0f+1 (matches reference)
        wa[p]  = (1.f - dx) * (1.f - dy);
        wb_[p] = (1.f - dx) * dy;
        wc_[p] = dx * (1.f - dy);
        wd_[p] = dx * dy;
        bool inreg = (x0 >= rx0) && (x1 <= rx1) && (y0 >= ry0) && (y1 <= ry1);
        // if x0==rx1 (only at image right edge) the +1 read lands in row pad,
        // value * wc(=0) -> harmless.
        a0[p] = inreg ? ((y0 - ry0) * LSTRIDE + (x0 - rx0)) : -1;
        a1[p] = (y1 - ry0) * LSTRIDE + (x0 - rx0);
    }

    const float* iplane = input + (size_t)b * C * HW;
    float* oplane = out + (size_t)b * C * HW;
    int col4 = cl << 2;         // staging col, 0..252

    for (int c = 0; c < C; ++c) {
        // ---- stage region into LDS (coalesced float4; rows of 592 B) ----
        const float* gc = iplane + (size_t)c * HW + ry0 * W + rx0;
        if (col4 < rw) {
            for (int r = rl; r < rh; r += 16) {
                float4 v = *(const float4*)(gc + r * W + col4);
                *(float4*)(&s[r * LSTRIDE + col4]) = v;
            }
        }
        __syncthreads();

        // ---- gather from LDS + FMA + coalesced store ----
        float* oc = oplane + (size_t)c * HW;
        #pragma unroll
        for (int p = 0; p < 4; ++p) {
            float v;
            if (a0[p] >= 0) {
                float v00 = s[a0[p]],  v01 = s[a0[p] + 1];
                float v10 = s[a1[p]],  v11 = s[a1[p] + 1];
                v = wa[p] * v00 + wc_[p] * v01 + wb_[p] * v10 + wd_[p] * v11;
            } else {
                // outlier (|flow|>APRON): recompute + global gather (P ~ 5e-7)
                int h = ty0 + rl + 16 * p;
                int w = tx0 + cl;
                int pix = h * W + w;
                float fx = flow[(b * 2 + 0) * HW + pix];
                float fy = flow[(b * 2 + 1) * HW + pix];
                float x = fminf(fmaxf((float)w + fx, 0.0f), (float)(W - 1));
                float y = fminf(fmaxf((float)h + fy, 0.0f), (float)(H - 1));
                float x0f = floorf(x), y0f = floorf(y);
                int x0 = (int)x0f, y0 = (int)y0f;
                int x1 = min(x0 + 1, W - 1), y1 = min(y0 + 1, H - 1);
                float dx = x - x0f, dy = y - y0f;
                const float* pch = iplane + (size_t)c * HW;
                v = (1.f - dx) * (1.f - dy) * pch[y0 * W + x0]
                  + (1.f - dx) * dy         * pch[y1 * W + x0]
                  + dx * (1.f - dy)         * pch[y0 * W + x1]
                  + dx * dy                 * pch[y1 * W + x1];
            }
            oc[opix0 + 16 * p * W] = v;
        }
        __syncthreads();   // WAR: next channel overwrites LDS
    }
}

extern "C" void kernel_launch(void* const* d_in, const int* in_sizes, int n_in,
                              void* d_out, int out_size, void* d_ws, size_t ws_size,
                              hipStream_t stream) {
    const float* input = (const float*)d_in[0];
    const float* flow  = (const float*)d_in[1];
    float* out = (float*)d_out;

    int grid = B * (H / TILE) * (W / TILE);   // 256 blocks -> 1 per CU
    warp_tile_kernel<<<grid, 1024, 0, stream>>>(input, flow, out);
}